// Round 1
// baseline (5119.325 us; speedup 1.0000x reference)
//
#include <hip/hip_runtime.h>
#include <cstdint>
#include <cmath>
#include <cstring>

// ---------------------------------------------------------------------------
// Problem constants
// ---------------------------------------------------------------------------
#define D16    16
#define CH     128
#define NBATCH 256
#define NSP    64
#define NRBF   32
#define NKK    50          // total multiplicity slots: 33 (order3) + 13 (order2) + 4 (order1)
#define NT3    816         // # sorted triples a0<=a1<=a2 in [0,16)
#define NT2    136         // # sorted pairs
#define LD3    160         // padded row stride for Usym3 (149 cols used)
#define LD2    64          // padded row stride for Usym2 (59 cols used)
#define U3_FLOATS (NT3*LD3)
#define U2_FLOATS (NT2*LD2)
#define U1_FLOATS 256
#define U_TOTAL   (U3_FLOATS+U2_FLOATS+U1_FLOATS)

// Device-resident constant data (written every launch via captured memcpy/kernels)
__device__ float g_U[U_TOTAL];
__device__ float g_ws[NSP*NKK*CH];

// kk -> (input array index, k within array); ARR_MUL = mul of each of the 12 W inputs
__device__ __constant__ int8_t KK_ARR[NKK] = {
  0,0,0,0,0, 1,1,1,1,1,1,1,1, 2,2,2,2,2,2,2,2,2,2, 3,3,3,3,3,3,3,3,3,3,
  4,4, 5,5,5, 6,6,6,6, 7,7,7,7, 8,9,10,11 };
__device__ __constant__ int8_t KK_K[NKK] = {
  0,1,2,3,4, 0,1,2,3,4,5,6,7, 0,1,2,3,4,5,6,7,8,9, 0,1,2,3,4,5,6,7,8,9,
  0,1, 0,1,2, 0,1,2,3, 0,1,2,3, 0,0,0,0 };
__device__ __constant__ int8_t ARR_MUL[12] = {5,8,10,10, 2,3,4,4, 1,1,1,1};

struct WPtrs { const float* p[12]; };

// ---------------------------------------------------------------------------
// Kernel A: per-species path weights  ws[s][kk][c] = sum_e embed[s][e]*W[e][k][c]
// ---------------------------------------------------------------------------
__global__ void weights_kernel(const float* __restrict__ embed, WPtrs wp) {
  int kk = blockIdx.x;
  int s  = blockIdx.y;
  int c  = threadIdx.x;
  int ai = KK_ARR[kk];
  int k  = KK_K[kk];
  int mul = ARR_MUL[ai];
  const float* __restrict__ W = wp.p[ai];
  float a = 0.f;
  #pragma unroll 8
  for (int e = 0; e < NRBF; ++e)
    a = fmaf(embed[s*NRBF + e], W[(e*mul + k)*CH + c], a);
  g_ws[(s*NKK + kk)*CH + c] = a;
}

// ---------------------------------------------------------------------------
// Kernel B helpers
// ---------------------------------------------------------------------------
template<int MUL, int DIM>
__device__ __forceinline__ void sweep3(const float* __restrict__ U3, int colbase,
                                       const float* __restrict__ xr,
                                       float* __restrict__ acc) {
  #pragma unroll
  for (int j = 0; j < MUL*DIM; ++j) acc[j] = 0.f;
  int t = 0;
  for (int a0 = 0; a0 < D16; ++a0) {
    float x0 = xr[a0];
    for (int a1 = a0; a1 < D16; ++a1) {
      float p = x0 * xr[a1];
      for (int a2 = a1; a2 < D16; ++a2) {
        float ft = p * xr[a2];
        const float* __restrict__ row = U3 + t*LD3 + colbase;
        #pragma unroll
        for (int j = 0; j < MUL*DIM; ++j) acc[j] = fmaf(row[j], ft, acc[j]);
        ++t;
      }
    }
  }
}

template<int MUL, int DIM>
__device__ __forceinline__ void sweep2(const float* __restrict__ U2, int colbase,
                                       const float* __restrict__ xr,
                                       float* __restrict__ acc) {
  #pragma unroll
  for (int j = 0; j < MUL*DIM; ++j) acc[j] = 0.f;
  int t = 0;
  for (int a0 = 0; a0 < D16; ++a0) {
    float x0 = xr[a0];
    for (int a1 = a0; a1 < D16; ++a1) {
      float ft = x0 * xr[a1];
      const float* __restrict__ row = U2 + t*LD2 + colbase;
      #pragma unroll
      for (int j = 0; j < MUL*DIM; ++j) acc[j] = fmaf(row[j], ft, acc[j]);
      ++t;
    }
  }
}

template<int MUL, int DIM>
__device__ __forceinline__ void foldw(const float* __restrict__ ws, int s, int c,
                                      int kkbase, int i0,
                                      const float* __restrict__ acc,
                                      float* __restrict__ outv) {
  #pragma unroll
  for (int k = 0; k < MUL; ++k) {
    float w = ws[(s*NKK + kkbase + k)*CH + c];
    #pragma unroll
    for (int i = 0; i < DIM; ++i)
      outv[i0 + i] = fmaf(w, acc[k*DIM + i], outv[i0 + i]);
  }
}

// ---------------------------------------------------------------------------
// Kernel B: main contraction. block = 1 batch row; 4 groups x 128 channels.
// ---------------------------------------------------------------------------
__global__ __launch_bounds__(512) void main_kernel(const float* __restrict__ x,
                                                   const int* __restrict__ index,
                                                   float* __restrict__ out) {
  __shared__ float xl[CH*17];
  __shared__ float osum[4*CH*17];
  const float* __restrict__ U3 = g_U;
  const float* __restrict__ U2 = g_U + U3_FLOATS;
  const float* __restrict__ U1 = g_U + U3_FLOATS + U2_FLOATS;
  const float* __restrict__ ws = g_ws;

  int tid = threadIdx.x;
  int g   = tid >> 7;
  int c   = tid & 127;
  int b   = blockIdx.x;
  int s   = index[b];

  if (g == 0) {
    const float4* xp = (const float4*)(x + (size_t)(b*CH + c)*D16);
    #pragma unroll
    for (int q = 0; q < 4; ++q) {
      float4 v = xp[q];
      xl[c*17 + q*4 + 0] = v.x; xl[c*17 + q*4 + 1] = v.y;
      xl[c*17 + q*4 + 2] = v.z; xl[c*17 + q*4 + 3] = v.w;
    }
  }
  __syncthreads();
  const float* xr = xl + c*17;

  float outv[16];
  #pragma unroll
  for (int i = 0; i < 16; ++i) outv[i] = 0.f;

  if (g == 0) {                       // order-3, ir = 3o (cols 79..148, kk 23..32)
    float acc[70];
    sweep3<10,7>(U3, 79, xr, acc);
    foldw<10,7>(ws, s, c, 23, 9, acc, outv);
  } else if (g == 1) {                // order-3, ir = 2e (cols 29..78, kk 13..22)
    float acc[50];
    sweep3<10,5>(U3, 29, xr, acc);
    foldw<10,5>(ws, s, c, 13, 4, acc, outv);
  } else if (g == 2) {                // order-3, ir = 0e + 1o
    { float acc[5];  sweep3<5,1>(U3, 0, xr, acc); foldw<5,1>(ws, s, c, 0, 0, acc, outv); }
    { float acc[24]; sweep3<8,3>(U3, 5, xr, acc); foldw<8,3>(ws, s, c, 5, 1, acc, outv); }
  } else {                            // order-2 all irs + order-1 all irs
    { float acc[2];  sweep2<2,1>(U2, 0,  xr, acc); foldw<2,1>(ws, s, c, 33, 0, acc, outv); }
    { float acc[9];  sweep2<3,3>(U2, 2,  xr, acc); foldw<3,3>(ws, s, c, 35, 1, acc, outv); }
    { float acc[20]; sweep2<4,5>(U2, 11, xr, acc); foldw<4,5>(ws, s, c, 38, 4, acc, outv); }
    { float acc[28]; sweep2<4,7>(U2, 31, xr, acc); foldw<4,7>(ws, s, c, 42, 9, acc, outv); }
    {
      float acc[16];
      #pragma unroll
      for (int j = 0; j < 16; ++j) acc[j] = 0.f;
      for (int a0 = 0; a0 < 16; ++a0) {
        float xa = xr[a0];
        #pragma unroll
        for (int j = 0; j < 16; ++j) acc[j] = fmaf(U1[a0*16 + j], xa, acc[j]);
      }
      foldw<1,1>(ws, s, c, 46, 0, acc + 0, outv);
      foldw<1,3>(ws, s, c, 47, 1, acc + 1, outv);
      foldw<1,5>(ws, s, c, 48, 4, acc + 4, outv);
      foldw<1,7>(ws, s, c, 49, 9, acc + 9, outv);
    }
  }

  #pragma unroll
  for (int i = 0; i < 16; ++i) osum[(g*CH + c)*17 + i] = outv[i];
  __syncthreads();

  if (g == 0) {
    #pragma unroll
    for (int i = 0; i < 16; ++i) {
      float r = osum[(0*CH + c)*17 + i] + osum[(1*CH + c)*17 + i]
              + osum[(2*CH + c)*17 + i] + osum[(3*CH + c)*17 + i];
      out[(size_t)(b*CH + c)*D16 + i] = r;
    }
  }
}

// ---------------------------------------------------------------------------
// Host-side: exact reproduction of np.random.default_rng(42) and U_BASIS
// ---------------------------------------------------------------------------
namespace host_rng {

typedef unsigned __int128 u128;

static inline u128 pcg_mult() {
  return (((u128)0x2360ed051fc65da4ULL) << 64) | 0x4385df649fccf645ULL;
}

struct PCG {
  u128 state, inc;
  inline uint64_t next() {
    state = state * pcg_mult() + inc;
    uint64_t hi = (uint64_t)(state >> 64), lo = (uint64_t)state;
    uint64_t x = hi ^ lo;
    unsigned rot = (unsigned)(hi >> 58);
    return (x >> rot) | (x << ((64u - rot) & 63u));
  }
  inline double nextd() { return (double)(next() >> 11) * (1.0 / 9007199254740992.0); }
};

static inline uint32_t hashmix(uint32_t v, uint32_t& hc) {
  v ^= hc; hc *= 0x931e8875u; v *= hc; v ^= v >> 16; return v;
}
static inline uint32_t mixfn(uint32_t x, uint32_t y) {
  uint32_t r = 0xca01f9ddu * x - 0x4973f715u * y; r ^= r >> 16; return r;
}

// SeedSequence(42) -> generate_state(4, uint64) -> PCG64 seeding
static void seed42(PCG& g) {
  uint32_t pool[4];
  uint32_t hc = 0x43b0d7e5u;              // INIT_A
  pool[0] = hashmix(42u, hc);
  for (int i = 1; i < 4; ++i) pool[i] = hashmix(0u, hc);
  for (int si = 0; si < 4; ++si)
    for (int di = 0; di < 4; ++di)
      if (si != di) pool[di] = mixfn(pool[di], hashmix(pool[si], hc));
  uint32_t hb = 0x8b51f9ddu;              // INIT_B
  uint32_t w32[8];
  for (int k = 0; k < 8; ++k) {
    uint32_t dv = pool[k & 3];
    dv ^= hb; hb *= 0x58f38dedu; dv *= hb; dv ^= dv >> 16;
    w32[k] = dv;
  }
  uint64_t s0 = (uint64_t)w32[0] | ((uint64_t)w32[1] << 32);
  uint64_t s1 = (uint64_t)w32[2] | ((uint64_t)w32[3] << 32);
  uint64_t s2 = (uint64_t)w32[4] | ((uint64_t)w32[5] << 32);
  uint64_t s3 = (uint64_t)w32[6] | ((uint64_t)w32[7] << 32);
  u128 initstate = ((u128)s0 << 64) | s1;
  u128 initseq   = ((u128)s2 << 64) | s3;
  g.inc   = (initseq << 1) | 1;
  g.state = g.inc;                         // step from state=0
  g.state += initstate;
  g.state = g.state * pcg_mult() + g.inc;  // second step
}

// Ziggurat tables regenerated with the canonical 256-strip recurrence (52-bit)
static double zig_w[256], zig_f[256];
static uint64_t zig_k[256];
static const double ZR = 3.6541528853610087963519472518;
static double ZRinv;

static void build_zig() {
  const double m1 = 4503599627370496.0;    // 2^52
  double fr   = std::exp(-0.5 * ZR * ZR);
  double tail = std::sqrt(M_PI * 0.5) * std::erfc(ZR / std::sqrt(2.0));
  double vn   = ZR * fr + tail;
  double q    = vn / fr;
  zig_k[0]   = (uint64_t)((ZR / q) * m1);
  zig_k[1]   = 0;
  zig_w[0]   = q / m1;
  zig_w[255] = ZR / m1;
  zig_f[0]   = 1.0;
  zig_f[255] = fr;
  double tn = ZR, dn = ZR;
  for (int i = 254; i >= 1; --i) {
    dn = std::sqrt(-2.0 * std::log(vn / dn + std::exp(-0.5 * dn * dn)));
    zig_k[i + 1] = (uint64_t)((dn / tn) * m1);
    tn = dn;
    zig_f[i] = std::exp(-0.5 * dn * dn);
    zig_w[i] = dn / m1;
  }
  ZRinv = 1.0 / ZR;
}

// verbatim port of numpy random_standard_normal
static double std_normal(PCG& g) {
  for (;;) {
    uint64_t r = g.next();
    int idx = (int)(r & 0xffu);
    r >>= 8;
    int sign = (int)(r & 1u);
    uint64_t rabs = (r >> 1) & 0x000fffffffffffffULL;
    double x = (double)rabs * zig_w[idx];
    if (sign) x = -x;
    if (rabs < zig_k[idx]) return x;
    if (idx == 0) {
      for (;;) {
        double xx = -ZRinv * std::log1p(-g.nextd());
        double yy = -std::log1p(-g.nextd());
        if (yy + yy > xx * xx)
          return ((rabs >> 8) & 1u) ? -(ZR + xx) : (ZR + xx);
      }
    } else {
      if ((zig_f[idx - 1] - zig_f[idx]) * g.nextd() + zig_f[idx] < std::exp(-0.5 * x * x))
        return x;
    }
  }
}

} // namespace host_rng

static float h_U[U_TOTAL];

static void build_U() {
  using namespace host_rng;
  build_zig();
  PCG g; seed42(g);

  static double S3[U3_FLOATS];
  static double S2[U2_FLOATS];
  static double S1[U1_FLOATS];
  std::memset(S3, 0, sizeof(S3));
  std::memset(S2, 0, sizeof(S2));
  std::memset(S1, 0, sizeof(S1));

  static int tmap[16][16][16];
  static int pmap[16][16];
  { int t = 0;
    for (int a0 = 0; a0 < 16; ++a0)
      for (int a1 = a0; a1 < 16; ++a1)
        for (int a2 = a1; a2 < 16; ++a2) tmap[a0][a1][a2] = t++; }
  { int t = 0;
    for (int a0 = 0; a0 < 16; ++a0)
      for (int a1 = a0; a1 < 16; ++a1) pmap[a0][a1] = t++; }

  const int muls3[4] = {5,8,10,10}, muls2[4] = {2,3,4,4};
  const int dims[4]  = {1,3,5,7};
  const int cb3[4]   = {0,5,29,79};
  const int cb2[4]   = {0,2,11,31};
  const int cb1[4]   = {0,1,4,9};

  static double nrm[16*16*16*10*7];   // max element count (order3, 3o)

  // ---- order 3 ----
  for (int ir = 0; ir < 4; ++ir) {
    int mul = muls3[ir], dim = dims[ir];
    long n = 4096L * mul * dim;
    for (long j = 0; j < n; ++j) nrm[j] = std_normal(g);
    long j = 0;
    for (int a0 = 0; a0 < 16; ++a0)
      for (int a1 = 0; a1 < 16; ++a1)
        for (int a2 = 0; a2 < 16; ++a2) {
          int s0 = a0, s1 = a1, s2 = a2, tswap;
          if (s0 > s1) { tswap = s0; s0 = s1; s1 = tswap; }
          if (s1 > s2) { tswap = s1; s1 = s2; s2 = tswap; }
          if (s0 > s1) { tswap = s0; s0 = s1; s1 = tswap; }
          int t = tmap[s0][s1][s2];
          for (int k = 0; k < mul; ++k)
            for (int i = 0; i < dim; ++i, ++j) {
              double u = g.nextd();
              if (u < 0.1) {
                float v = (float)nrm[j];
                v = v / 3.0f;
                S3[t*LD3 + cb3[ir] + k*dim + i] += (double)v;
              }
            }
        }
  }
  // ---- order 2 ----
  for (int ir = 0; ir < 4; ++ir) {
    int mul = muls2[ir], dim = dims[ir];
    long n = 256L * mul * dim;
    for (long j = 0; j < n; ++j) nrm[j] = std_normal(g);
    long j = 0;
    for (int a0 = 0; a0 < 16; ++a0)
      for (int a1 = 0; a1 < 16; ++a1) {
        int s0 = a0 < a1 ? a0 : a1;
        int s1 = a0 < a1 ? a1 : a0;
        int t = pmap[s0][s1];
        for (int k = 0; k < mul; ++k)
          for (int i = 0; i < dim; ++i, ++j) {
            double u = g.nextd();
            if (u < 0.1) {
              float v = (float)nrm[j];
              v = v / 2.0f;
              S2[t*LD2 + cb2[ir] + k*dim + i] += (double)v;
            }
          }
      }
  }
  // ---- order 1 ----
  for (int ir = 0; ir < 4; ++ir) {
    int dim = dims[ir];
    long n = 16L * dim;
    for (long j = 0; j < n; ++j) nrm[j] = std_normal(g);
    long j = 0;
    for (int a0 = 0; a0 < 16; ++a0)
      for (int i = 0; i < dim; ++i, ++j) {
        double u = g.nextd();
        if (u < 0.1) {
          float v = (float)nrm[j];   // /1 exact
          S1[a0*16 + cb1[ir] + i] += (double)v;
        }
      }
  }

  for (int i = 0; i < U3_FLOATS; ++i) h_U[i] = (float)S3[i];
  for (int i = 0; i < U2_FLOATS; ++i) h_U[U3_FLOATS + i] = (float)S2[i];
  for (int i = 0; i < U1_FLOATS; ++i) h_U[U3_FLOATS + U2_FLOATS + i] = (float)S1[i];
}

// ---------------------------------------------------------------------------
extern "C" void kernel_launch(void* const* d_in, const int* in_sizes, int n_in,
                              void* d_out, int out_size, void* d_ws, size_t ws_size,
                              hipStream_t stream) {
  (void)in_sizes; (void)n_in; (void)d_ws; (void)ws_size; (void)out_size;

  build_U();   // deterministic, recomputed every call; runs only at capture time

  const float* x     = (const float*)d_in[0];
  const int*   index = (const int*)d_in[1];
  const float* embed = (const float*)d_in[2];
  WPtrs wp;
  for (int i = 0; i < 12; ++i) wp.p[i] = (const float*)d_in[3 + i];

  void* uptr = nullptr;
  hipGetSymbolAddress(&uptr, HIP_SYMBOL(g_U));
  hipMemcpyAsync(uptr, h_U, sizeof(h_U), hipMemcpyHostToDevice, stream);

  dim3 gw(NKK, NSP);
  weights_kernel<<<gw, CH, 0, stream>>>(embed, wp);
  main_kernel<<<NBATCH, 512, 0, stream>>>(x, index, (float*)d_out);
}